// Round 4
// baseline (251.358 us; speedup 1.0000x reference)
//
#include <hip/hip_runtime.h>

// LaBramChannelPatcher: [B=16, W=32, T=1000, C=64] fp32 ->
//   patches [B, W, C*nt=320, P=200]  (== per-(b,w) transpose [T,C] -> [C,T])
//   channel_indices [320] = repeat(arange(64), 5)
//   time_indices    [320] = tile(arange(5), 64)
//
// Memory-bound transpose. 320-thread blocks (exact 5 items/thread -> full
// unroll), register-batched loads/stores for MLP, nontemporal output stores
// via native ext_vector_type (HIP float4 is a class -> builtin rejects it).

#define TDIM 1000
#define CDIM 64
#define TT   100        // t-rows per tile (1000 = 10 * 100)
#define LSTR 65         // LDS row stride (odd -> 2-way-max bank aliasing)
#define NTILE 10
#define PATCH_ELEMS 32768000   // 16*32*320*200

typedef float v4f __attribute__((ext_vector_type(4)));

__global__ __launch_bounds__(320) void labram_patcher_kernel(
    const float* __restrict__ in, float* __restrict__ out)
{
    __shared__ float lds[TT * LSTR];   // lds[ti][c], stride 65 words

    const int tid  = threadIdx.x;          // 0..319
    const int tile = blockIdx.x % NTILE;
    const int bw   = blockIdx.x / NTILE;   // 0..511  (b*32 + w)
    const int t0   = tile * TT;

    // ---- Phase 1: 5 coalesced float4 loads per thread, all in flight,
    //      then scatter into lds[ti][c]. 1600 float4 per block. ----
    const v4f* in4 = (const v4f*)(in + (size_t)(bw * TDIM + t0) * CDIM);
    v4f v[5];
#pragma unroll
    for (int k = 0; k < 5; ++k)
        v[k] = in4[tid + 320 * k];
#pragma unroll
    for (int k = 0; k < 5; ++k) {
        int idx = tid + 320 * k;
        int ti  = idx >> 4;        // 0..99
        int c4  = idx & 15;        // 0..15
        int base = ti * LSTR + c4 * 4;
        lds[base + 0] = v[k].x;
        lds[base + 1] = v[k].y;
        lds[base + 2] = v[k].z;
        lds[base + 3] = v[k].w;
    }
    __syncthreads();

    // ---- Phase 2: 20 LDS gathers then 5 coalesced float4 stores per thread.
    //      (c-major order keeps stores contiguous along t.) ----
    v4f o[5];
    int cc[5], jj[5];
#pragma unroll
    for (int k = 0; k < 5; ++k) {
        int idx = tid + 320 * k;   // 0..1599 over (c, j)
        int c   = idx / 25;
        int j   = idx - c * 25;
        int ti  = j * 4;
        cc[k] = c; jj[k] = j;
        o[k].x = lds[(ti + 0) * LSTR + c];
        o[k].y = lds[(ti + 1) * LSTR + c];
        o[k].z = lds[(ti + 2) * LSTR + c];
        o[k].w = lds[(ti + 3) * LSTR + c];
    }
#pragma unroll
    for (int k = 0; k < 5; ++k) {
        size_t off = (size_t)(bw * CDIM + cc[k]) * TDIM + (t0 + jj[k] * 4);
        __builtin_nontemporal_store(o[k], (v4f*)(out + off));
    }

    // ---- Index outputs (tiny): block 0, one entry per thread ----
    if (blockIdx.x == 0) {
        out[PATCH_ELEMS + tid]       = (float)(tid / 5);  // channel_indices
        out[PATCH_ELEMS + 320 + tid] = (float)(tid % 5);  // time_indices
    }
}

extern "C" void kernel_launch(void* const* d_in, const int* in_sizes, int n_in,
                              void* d_out, int out_size, void* d_ws, size_t ws_size,
                              hipStream_t stream) {
    const float* in = (const float*)d_in[0];
    float* out = (float*)d_out;
    // 512 (b,w) slices * 10 t-tiles
    dim3 grid(512 * NTILE);
    dim3 block(320);
    labram_patcher_kernel<<<grid, block, 0, stream>>>(in, out);
}